// Round 7
// baseline (3472.110 us; speedup 1.0000x reference)
//
#include <hip/hip_runtime.h>
#include <hip/hip_bf16.h>
#include <math.h>

#define NS    8
#define NNI   32
#define NCI   128
#define NHH   16
#define NWW   16
#define NCO   128
#define NFF   1152
#define NLL   256
#define LAMV  1152.0f

typedef short s8v __attribute__((ext_vector_type(8)));
typedef float f4v __attribute__((ext_vector_type(4)));

#define AS1 __attribute__((address_space(1)))
#define AS3 __attribute__((address_space(3)))

// ---------------------------------------------------------------- sqrt_prec table
__global__ void k_sp(const float* __restrict__ lp, float* __restrict__ sp) {
  int t = threadIdx.x;
  if (t < NNI) sp[t] = expf(0.5f * lp[t]);
}

// ---------------------------------------------------------------- build Xu (bf16), SB s per launch
__global__ __launch_bounds__(256) void k_build_Xu(const float* __restrict__ X,
                                                  const float* __restrict__ sp,
                                                  unsigned short* __restrict__ Xu) {
  unsigned z = blockIdx.y;
  unsigned idx = blockIdx.x * 256u + threadIdx.x;   // < 1152*8192
  unsigned m = idx & 8191u;
  unsigned f = idx >> 13;
  unsigned n = m >> 8, l = m & 255u, h = l >> 4, w = l & 15u;
  unsigned c = f / 9u, a = f - 9u * c;
  unsigned ki = a / 3u, kj = a - 3u * ki;
  int hi = (int)(h + ki) - 1, wi = (int)(w + kj) - 1;
  float v = 0.f;
  if (hi >= 0 && hi < NHH && wi >= 0 && wi < NWW)
    v = X[(size_t)z * 1048576 + (((size_t)n * NCI + c) << 8) + (unsigned)(hi * NWW + wi)];
  __hip_bfloat16 hv = __float2bfloat16(sp[n] * v);
  Xu[(size_t)z * (NFF * 8192) + idx] = *(unsigned short*)&hv;
}

__global__ __launch_bounds__(256) void k_build_B(const float* __restrict__ u,
                                                 const float* __restrict__ sp,
                                                 unsigned short* __restrict__ Bm) {
  unsigned idx = blockIdx.x * 256u + threadIdx.x;   // < 1,048,576
  unsigned m = idx & 8191u;
  unsigned c = idx >> 13;
  unsigned n = m >> 8, l = m & 255u;
  __hip_bfloat16 hv = __float2bfloat16(sp[n] * u[((size_t)n * NCO + c) * NLL + l]);
  Bm[idx] = *(unsigned short*)&hv;
}

__global__ void k_diag_init(float* __restrict__ prec) {
  int s = blockIdx.y;
  int i = blockIdx.x * 256 + threadIdx.x;
  if (i < NFF) prec[(size_t)s * NFF * NFF + (size_t)i * NFF + i] = LAMV;
}

// ---------------------------------------------------------------- MFMA bf16 GEMM, SB s per launch
// kLen = K per block; direct!=0 -> exactly one block per (tile,s): plain stores + LAM on diag
__global__ __launch_bounds__(256) void k_mfma(const unsigned short* __restrict__ XuBase,
                                              const unsigned short* __restrict__ Bm,
                                              float* __restrict__ prec,
                                              float* __restrict__ XLY,
                                              int kLen, int direct) {
  __shared__ unsigned short As[8192];
  __shared__ unsigned short Bs[8192];
  int z = blockIdx.z;
  const unsigned short* Xu = XuBase + (size_t)z * (NFF * 8192);
  prec += (size_t)z * NFF * NFF;
  XLY += (size_t)z * NFF * NCO;
  int bx = blockIdx.x;
  int row0, col0;
  const unsigned short* Ag;
  const unsigned short* Bg;
  bool isXLX;
  if (bx < 45) {
    int b = 0;
    while ((b + 1) * (b + 2) / 2 <= bx) b++;
    row0 = b * 128;
    col0 = (bx - b * (b + 1) / 2) * 128;
    Bg = Xu + (size_t)col0 * 8192;
    isXLX = true;
  } else {
    row0 = (bx - 45) * 128;
    col0 = 0;
    Bg = Bm;
    isXLX = false;
  }
  Ag = Xu + (size_t)row0 * 8192;

  int t = threadIdx.x;
  int lane = t & 63, w = t >> 6;
  int wm = w & 1, wn = w >> 1;
  int n16 = lane & 15, q = lane >> 4;
  int srow = lane >> 3, sch = lane & 7;

  f4v acc[4][4];
#pragma unroll
  for (int i = 0; i < 4; ++i)
#pragma unroll
    for (int j = 0; j < 4; ++j) acc[i][j] = (f4v)0.f;

  int kBase = blockIdx.y * kLen;
  for (int k0 = kBase; k0 < kBase + kLen; k0 += 64) {
    __syncthreads();
#pragma unroll
    for (int it = 0; it < 4; ++it) {
      int rA = (w * 4 + it) * 8 + srow;
      int cA = (sch - rA) & 7;
      const unsigned short* gpa = Ag + (size_t)rA * 8192 + k0 + cA * 8;
      const unsigned short* gpb = Bg + (size_t)rA * 8192 + k0 + cA * 8;
      __builtin_amdgcn_global_load_lds((AS1 const void*)gpa,
                                       (AS3 void*)&As[(w * 4 + it) * 512], 16, 0, 0);
      __builtin_amdgcn_global_load_lds((AS1 const void*)gpb,
                                       (AS3 void*)&Bs[(w * 4 + it) * 512], 16, 0, 0);
    }
    __syncthreads();
#pragma unroll
    for (int kk = 0; kk < 2; ++kk) {
      s8v af[4], bf[4];
#pragma unroll
      for (int im = 0; im < 4; ++im) {
        int r = wm * 64 + im * 16 + n16;
        int slot = ((kk * 4 + q) + r) & 7;
        af[im] = *(const s8v*)&As[r * 64 + slot * 8];
      }
#pragma unroll
      for (int in = 0; in < 4; ++in) {
        int r = wn * 64 + in * 16 + n16;
        int slot = ((kk * 4 + q) + r) & 7;
        bf[in] = *(const s8v*)&Bs[r * 64 + slot * 8];
      }
#pragma unroll
      for (int im = 0; im < 4; ++im)
#pragma unroll
        for (int in = 0; in < 4; ++in)
          acc[im][in] = __builtin_amdgcn_mfma_f32_16x16x32_bf16(af[im], bf[in], acc[im][in], 0, 0, 0);
    }
  }

#pragma unroll
  for (int im = 0; im < 4; ++im)
#pragma unroll
    for (int in = 0; in < 4; ++in) {
      int gr = row0 + wm * 64 + im * 16 + q * 4;
      int gc = (isXLX ? col0 : 0) + wn * 64 + in * 16 + n16;
      if (direct) {
        if (isXLX) {
#pragma unroll
          for (int tt = 0; tt < 4; ++tt)
            prec[(size_t)(gr + tt) * NFF + gc] =
                acc[im][in][tt] + ((gr + tt) == gc ? LAMV : 0.f);
        } else {
#pragma unroll
          for (int tt = 0; tt < 4; ++tt)
            XLY[(size_t)(gr + tt) * NCO + gc] = acc[im][in][tt];
        }
      } else {
        if (isXLX) {
#pragma unroll
          for (int tt = 0; tt < 4; ++tt)
            atomicAdd(&prec[(size_t)(gr + tt) * NFF + gc], acc[im][in][tt]);
        } else {
#pragma unroll
          for (int tt = 0; tt < 4; ++tt)
            atomicAdd(&XLY[(size_t)(gr + tt) * NCO + gc], acc[im][in][tt]);
        }
      }
    }
}

// ---------------------------------------------------------------- Cholesky: diag for p=0 (single wave)
__global__ __launch_bounds__(64) void k_chol_diag(float* __restrict__ P, int p) {
  int s = blockIdx.x;
  float* Ps = P + (size_t)s * NFF * NFF + (size_t)(p * 64) * NFF + p * 64;
  __shared__ float D[64][65];
  int t = threadIdx.x;
  for (int e = t; e < 1024; e += 64) {
    int r = e >> 4, cq = (e & 15) * 4;
    float4 v = *(const float4*)(Ps + (size_t)r * NFF + cq);
    D[r][cq + 0] = v.x; D[r][cq + 1] = v.y; D[r][cq + 2] = v.z; D[r][cq + 3] = v.w;
  }
  __syncthreads();
  for (int j = 0; j < 64; ++j) {
    float dj = sqrtf(D[j][j]);
    float inv = 1.0f / dj;
    float lij = 0.f;
    if (t == j) D[j][j] = dj;
    if (t > j) { lij = D[t][j] * inv; D[t][j] = lij; }
    __syncthreads();
    for (int k = j + 1; k <= t; ++k) D[t][k] = fmaf(-lij, D[k][j], D[t][k]);
    __syncthreads();
  }
  for (int e = t; e < 1024; e += 64) {
    int r = e >> 4, cq = (e & 15) * 4;
    float4 v;
    v.x = D[r][cq + 0]; v.y = D[r][cq + 1]; v.z = D[r][cq + 2]; v.w = D[r][cq + 3];
    *(float4*)(Ps + (size_t)r * NFF + cq) = v;
  }
}

// ---------------------------------------------------------------- fused chol step p (R6, unchanged)
__global__ __launch_bounds__(256) void k_chol_step(float* __restrict__ P, int p) {
  int s = blockIdx.y;
  float* Ps = P + (size_t)s * NFF * NFF;
  int idx = blockIdx.x;
  int b = 0;
  while ((b + 1) * (b + 2) / 2 <= idx) b++;
  int c = idx - b * (b + 1) / 2;
  int bi = p + 1 + b, bj = p + 1 + c;
  int pc = p * 64;
  __shared__ float Ld[64][65];
  __shared__ float Ai[64][65];
  __shared__ float Aj[64][65];
  int t = threadIdx.x;
  int w = t >> 6, lane = t & 63;
  for (int e = t; e < 4096; e += 256) {
    int r = e >> 6, cc = e & 63;
    Ld[r][cc] = Ps[(size_t)(pc + r) * NFF + pc + cc];
    Ai[r][cc] = Ps[(size_t)(bi * 64 + r) * NFF + pc + cc];
  }
  if (c < b)
    for (int e = t; e < 4096; e += 256) {
      int r = e >> 6, cc = e & 63;
      Aj[r][cc] = Ps[(size_t)(bj * 64 + r) * NFF + pc + cc];
    }
  __syncthreads();
  if (w == 0) {
    for (int j = 0; j < 64; ++j) {
      float v = Ai[lane][j] / Ld[j][j];
      Ai[lane][j] = v;
      for (int k = j + 1; k < 64; ++k) Ai[lane][k] = fmaf(-v, Ld[k][j], Ai[lane][k]);
    }
  } else if (w == 1 && c < b) {
    for (int j = 0; j < 64; ++j) {
      float v = Aj[lane][j] / Ld[j][j];
      Aj[lane][j] = v;
      for (int k = j + 1; k < 64; ++k) Aj[lane][k] = fmaf(-v, Ld[k][j], Aj[lane][k]);
    }
  }
  __syncthreads();
  int tx = t & 15, ty = t >> 4;
  if (c == b) {
    for (int e = t; e < 4096; e += 256) {
      int r = e >> 6, cc = e & 63;
      Ps[(size_t)(pc + cc) * NFF + bi * 64 + r] = Ai[r][cc];
    }
    float acc[4][4];
#pragma unroll
    for (int a = 0; a < 4; ++a)
#pragma unroll
      for (int b2 = 0; b2 < 4; ++b2) acc[a][b2] = 0.f;
#pragma unroll 8
    for (int kc = 0; kc < 64; ++kc) {
      float av[4], bv[4];
#pragma unroll
      for (int a = 0; a < 4; ++a) av[a] = Ai[ty * 4 + a][kc];
#pragma unroll
      for (int b2 = 0; b2 < 4; ++b2) bv[b2] = Ai[tx * 4 + b2][kc];
#pragma unroll
      for (int a = 0; a < 4; ++a)
#pragma unroll
        for (int b2 = 0; b2 < 4; ++b2) acc[a][b2] = fmaf(av[a], bv[b2], acc[a][b2]);
    }
    if (b == 0) {
      __syncthreads();
#pragma unroll
      for (int a = 0; a < 4; ++a) {
        float4 g = *(const float4*)&Ps[(size_t)(bi * 64 + ty * 4 + a) * NFF + bi * 64 + tx * 4];
        Aj[ty * 4 + a][tx * 4 + 0] = g.x - acc[a][0];
        Aj[ty * 4 + a][tx * 4 + 1] = g.y - acc[a][1];
        Aj[ty * 4 + a][tx * 4 + 2] = g.z - acc[a][2];
        Aj[ty * 4 + a][tx * 4 + 3] = g.w - acc[a][3];
      }
      __syncthreads();
      for (int j = 0; j < 64; ++j) {
        if (w == 0) {
          float dj = sqrtf(Aj[j][j]);
          float inv = 1.0f / dj;
          float lij = 0.f;
          if (lane == j) Aj[j][j] = dj;
          if (lane > j) { lij = Aj[lane][j] * inv; Aj[lane][j] = lij; }
          for (int k = j + 1; k <= lane; ++k) Aj[lane][k] = fmaf(-lij, Aj[k][j], Aj[lane][k]);
        }
        __syncthreads();
      }
      for (int e = t; e < 4096; e += 256) {
        int r = e >> 6, cc = e & 63;
        Ps[(size_t)(bi * 64 + r) * NFF + bi * 64 + cc] = Aj[r][cc];
      }
    } else {
#pragma unroll
      for (int a = 0; a < 4; ++a) {
        float4* cp = (float4*)&Ps[(size_t)(bi * 64 + ty * 4 + a) * NFF + bi * 64 + tx * 4];
        float4 cv = *cp;
        cv.x -= acc[a][0]; cv.y -= acc[a][1]; cv.z -= acc[a][2]; cv.w -= acc[a][3];
        *cp = cv;
      }
    }
  } else {
    float acc[4][4];
#pragma unroll
    for (int a = 0; a < 4; ++a)
#pragma unroll
      for (int b2 = 0; b2 < 4; ++b2) acc[a][b2] = 0.f;
#pragma unroll 8
    for (int kc = 0; kc < 64; ++kc) {
      float av[4], bv[4];
#pragma unroll
      for (int a = 0; a < 4; ++a) av[a] = Ai[ty * 4 + a][kc];
#pragma unroll
      for (int b2 = 0; b2 < 4; ++b2) bv[b2] = Aj[tx * 4 + b2][kc];
#pragma unroll
      for (int a = 0; a < 4; ++a)
#pragma unroll
        for (int b2 = 0; b2 < 4; ++b2) acc[a][b2] = fmaf(av[a], bv[b2], acc[a][b2]);
    }
#pragma unroll
    for (int a = 0; a < 4; ++a) {
      float4* cp = (float4*)&Ps[(size_t)(bi * 64 + ty * 4 + a) * NFF + bj * 64 + tx * 4];
      float4 cv = *cp;
      cv.x -= acc[a][0]; cv.y -= acc[a][1]; cv.z -= acc[a][2]; cv.w -= acc[a][3];
      *cp = cv;
    }
  }
}

// ---------------------------------------------------------------- inverse diag blocks + logdet
__global__ __launch_bounds__(64) void k_invdiag(const float* __restrict__ P,
                                                float* __restrict__ W,
                                                float* __restrict__ accum) {
  int ib = blockIdx.x, s = blockIdx.y;
  const float* Ps = P + (size_t)s * NFF * NFF + (size_t)(ib * 64) * NFF + ib * 64;
  float* Ws = W + (size_t)s * NFF * NFF + (size_t)(ib * 64) * NFF + ib * 64;
  __shared__ float Lt[64][65];
  __shared__ float xc[64][66];
  int t = threadIdx.x;
  for (int e = t; e < 4096; e += 64)
    Lt[e >> 6][e & 63] = Ps[(size_t)(e >> 6) * NFF + (e & 63)];
  __syncthreads();
  float lg = logf(Lt[t][t]);
#pragma unroll
  for (int o = 32; o; o >>= 1) lg += __shfl_down(lg, o, 64);
  if (t == 0) atomicAdd(&accum[s * 4 + 2], 2.f * lg);
  for (int j = 0; j < 64; ++j) {
    float v = (j == t) ? 1.f : 0.f;
    for (int k = t; k < j; ++k) v = fmaf(-Lt[j][k], xc[k][t], v);
    xc[j][t] = v / Lt[j][j];
  }
  for (int j = 0; j < 64; ++j)
    Ws[(size_t)j * NFF + t] = (j >= t) ? xc[j][t] : 0.f;
}

// ---------------------------------------------------------------- inverse column walker v2
// block = (column j, s). Full 64-col width, register double-buffered tile prefetch.
__global__ __launch_bounds__(256) void k_invcol(const float* __restrict__ P,
                                                float* __restrict__ W) {
  int j = blockIdx.x, s = blockIdx.y;     // grid (17, 8)
  const float* Ps = P + (size_t)s * NFF * NFF;
  float* Ws = W + (size_t)s * NFF * NFF;
  int c0 = j * 64;
  __shared__ float Lk[64][68];   // Lk[q][r] = L[i][kb][r][q] (from transposed-upper copy)
  __shared__ float Bt[64][68];   // W[kb][j]
  __shared__ float Ss[64][68];   // S
  __shared__ float Wt[64][68];   // W[i][i] transposed
  int t = threadIdx.x, tx = t & 15, ty = t >> 4;
  int lr = t >> 2, lc = (t & 3) * 4;
  for (int i = j + 1; i < 18; ++i) {
    float acc[4][4];
#pragma unroll
    for (int a = 0; a < 4; ++a)
#pragma unroll
      for (int b = 0; b < 4; ++b) acc[a][b] = 0.f;
    float4 pL[4], pB[4];
    {
      const float* Lp = Ps + (size_t)(j * 64 + lr) * NFF + i * 64;
      const float* Wp = Ws + (size_t)(j * 64 + lr) * NFF + c0;
#pragma unroll
      for (int it = 0; it < 4; ++it) {
        pL[it] = *(const float4*)(Lp + lc + it * 16);
        pB[it] = *(const float4*)(Wp + lc + it * 16);
      }
    }
    for (int kb = j; kb < i; ++kb) {
      __syncthreads();                      // prior LDS reads done
#pragma unroll
      for (int it = 0; it < 4; ++it) {
        *(float4*)&Lk[lr][lc + it * 16] = pL[it];
        *(float4*)&Bt[lr][lc + it * 16] = pB[it];
      }
      __syncthreads();
      if (kb + 1 < i) {                     // prefetch next tile into regs
        const float* Lp = Ps + (size_t)((kb + 1) * 64 + lr) * NFF + i * 64;
        const float* Wp = Ws + (size_t)((kb + 1) * 64 + lr) * NFF + c0;
#pragma unroll
        for (int it = 0; it < 4; ++it) {
          pL[it] = *(const float4*)(Lp + lc + it * 16);
          pB[it] = *(const float4*)(Wp + lc + it * 16);
        }
      }
#pragma unroll 4
      for (int q = 0; q < 64; ++q) {
        float4 av = *(const float4*)&Lk[q][ty * 4];
        float4 bv = *(const float4*)&Bt[q][tx * 4];
        acc[0][0] = fmaf(av.x, bv.x, acc[0][0]); acc[0][1] = fmaf(av.x, bv.y, acc[0][1]);
        acc[0][2] = fmaf(av.x, bv.z, acc[0][2]); acc[0][3] = fmaf(av.x, bv.w, acc[0][3]);
        acc[1][0] = fmaf(av.y, bv.x, acc[1][0]); acc[1][1] = fmaf(av.y, bv.y, acc[1][1]);
        acc[1][2] = fmaf(av.y, bv.z, acc[1][2]); acc[1][3] = fmaf(av.y, bv.w, acc[1][3]);
        acc[2][0] = fmaf(av.z, bv.x, acc[2][0]); acc[2][1] = fmaf(av.z, bv.y, acc[2][1]);
        acc[2][2] = fmaf(av.z, bv.z, acc[2][2]); acc[2][3] = fmaf(av.z, bv.w, acc[2][3]);
        acc[3][0] = fmaf(av.w, bv.x, acc[3][0]); acc[3][1] = fmaf(av.w, bv.y, acc[3][1]);
        acc[3][2] = fmaf(av.w, bv.z, acc[3][2]); acc[3][3] = fmaf(av.w, bv.w, acc[3][3]);
      }
    }
    __syncthreads();
#pragma unroll
    for (int a = 0; a < 4; ++a) {
      float4 v; v.x = acc[a][0]; v.y = acc[a][1]; v.z = acc[a][2]; v.w = acc[a][3];
      *(float4*)&Ss[ty * 4 + a][tx * 4] = v;
    }
    {
      const float* Dp = Ws + (size_t)(i * 64 + lr) * NFF + i * 64;
#pragma unroll
      for (int it = 0; it < 4; ++it) {
        float4 wv = *(const float4*)(Dp + lc + it * 16);
        Wt[lc + it * 16 + 0][lr] = wv.x; Wt[lc + it * 16 + 1][lr] = wv.y;
        Wt[lc + it * 16 + 2][lr] = wv.z; Wt[lc + it * 16 + 3][lr] = wv.w;
      }
    }
    __syncthreads();
    float a2[4][4];
#pragma unroll
    for (int a = 0; a < 4; ++a)
#pragma unroll
      for (int b = 0; b < 4; ++b) a2[a][b] = 0.f;
#pragma unroll 4
    for (int q = 0; q < 64; ++q) {
      float4 av = *(const float4*)&Wt[q][ty * 4];
      float4 bv = *(const float4*)&Ss[q][tx * 4];
      a2[0][0] = fmaf(av.x, bv.x, a2[0][0]); a2[0][1] = fmaf(av.x, bv.y, a2[0][1]);
      a2[0][2] = fmaf(av.x, bv.z, a2[0][2]); a2[0][3] = fmaf(av.x, bv.w, a2[0][3]);
      a2[1][0] = fmaf(av.y, bv.x, a2[1][0]); a2[1][1] = fmaf(av.y, bv.y, a2[1][1]);
      a2[1][2] = fmaf(av.y, bv.z, a2[1][2]); a2[1][3] = fmaf(av.y, bv.w, a2[1][3]);
      a2[2][0] = fmaf(av.z, bv.x, a2[2][0]); a2[2][1] = fmaf(av.z, bv.y, a2[2][1]);
      a2[2][2] = fmaf(av.z, bv.z, a2[2][2]); a2[2][3] = fmaf(av.z, bv.w, a2[2][3]);
      a2[3][0] = fmaf(av.w, bv.x, a2[3][0]); a2[3][1] = fmaf(av.w, bv.y, a2[3][1]);
      a2[3][2] = fmaf(av.w, bv.z, a2[3][2]); a2[3][3] = fmaf(av.w, bv.w, a2[3][3]);
    }
#pragma unroll
    for (int a = 0; a < 4; ++a) {
      float4 o;
      o.x = -a2[a][0]; o.y = -a2[a][1]; o.z = -a2[a][2]; o.w = -a2[a][3];
      *(float4*)(Ws + (size_t)(i * 64 + ty * 4 + a) * NFF + c0 + tx * 4) = o;
    }
  }
}

// ---------------------------------------------------------------- apply: t1R = W*XLY + Z (+sumZ^2)
__global__ __launch_bounds__(256) void k_app1(const float* __restrict__ W,
                                              const float* __restrict__ XLY,
                                              const float* __restrict__ Z,
                                              float* __restrict__ t1R,
                                              float* __restrict__ accum) {
  int rb = blockIdx.x, ch = blockIdx.y, s = blockIdx.z;
  int r0 = rb * 64, c0 = ch * 64;
  const float* Ws = W + (size_t)s * NFF * NFF;
  const float* Ys = XLY + (size_t)s * NFF * NCO;
  const float* Zs = Z + (size_t)s * NFF * NCO;
  float* Os = t1R + (size_t)s * NFF * NCO;
  __shared__ float As_[16][68];
  __shared__ float Bs_[16][68];
  __shared__ float red[256];
  int t = threadIdx.x, tx = t & 15, ty = t >> 4;
  float acc[4][4];
#pragma unroll
  for (int a = 0; a < 4; ++a)
#pragma unroll
    for (int b = 0; b < 4; ++b) acc[a][b] = 0.f;
  int kmax = r0 + 64;
  for (int k0 = 0; k0 < kmax; k0 += 16) {
    float4 a = *(const float4*)(Ws + (size_t)(r0 + (t >> 2)) * NFF + k0 + (t & 3) * 4);
    float4 bb = *(const float4*)(Ys + (size_t)(k0 + (t >> 4)) * NCO + c0 + (t & 15) * 4);
    __syncthreads();
    As_[(t & 3) * 4 + 0][t >> 2] = a.x; As_[(t & 3) * 4 + 1][t >> 2] = a.y;
    As_[(t & 3) * 4 + 2][t >> 2] = a.z; As_[(t & 3) * 4 + 3][t >> 2] = a.w;
    *(float4*)&Bs_[t >> 4][(t & 15) * 4] = bb;
    __syncthreads();
#pragma unroll
    for (int kk = 0; kk < 16; ++kk) {
      float av[4], bv[4];
#pragma unroll
      for (int a2 = 0; a2 < 4; ++a2) av[a2] = As_[kk][ty * 4 + a2];
      *(float4*)&bv[0] = *(const float4*)&Bs_[kk][tx * 4];
#pragma unroll
      for (int a2 = 0; a2 < 4; ++a2)
#pragma unroll
        for (int b2 = 0; b2 < 4; ++b2) acc[a2][b2] = fmaf(av[a2], bv[b2], acc[a2][b2]);
    }
  }
  float z2 = 0.f;
#pragma unroll
  for (int a2 = 0; a2 < 4; ++a2) {
    int row = r0 + ty * 4 + a2;
    const float* zp = Zs + (size_t)row * NCO + c0 + tx * 4;
    float* op = Os + (size_t)row * NCO + c0 + tx * 4;
    float4 z0 = *(const float4*)zp;
    float4 v0;
    v0.x = acc[a2][0] + z0.x; v0.y = acc[a2][1] + z0.y;
    v0.z = acc[a2][2] + z0.z; v0.w = acc[a2][3] + z0.w;
    z2 += z0.x * z0.x + z0.y * z0.y + z0.z * z0.z + z0.w * z0.w;
    *(float4*)op = v0;
  }
  __syncthreads();
  red[t] = z2;
  __syncthreads();
  for (int o = 128; o > 0; o >>= 1) {
    if (t < o) red[t] += red[t + o];
    __syncthreads();
  }
  if (t == 0) atomicAdd(&accum[s * 4 + 1], red[0]);
}

// ---------------------------------------------------------------- apply: sample = W^T * t1R (+sum S^2)
__global__ __launch_bounds__(256) void k_app2(const float* __restrict__ W,
                                              const float* __restrict__ t1R,
                                              float* __restrict__ sout,
                                              float* __restrict__ accum) {
  int rb = blockIdx.x, ch = blockIdx.y, s = blockIdx.z;
  int r0 = rb * 64, c0 = ch * 64;
  const float* Ws = W + (size_t)s * NFF * NFF;
  const float* Rs = t1R + (size_t)s * NFF * NCO;
  float* Op = sout + (size_t)s * NCO * NFF;
  __shared__ float As_[16][68];
  __shared__ float Bs_[16][68];
  __shared__ float red[256];
  int t = threadIdx.x, tx = t & 15, ty = t >> 4;
  float acc[4][4];
#pragma unroll
  for (int a = 0; a < 4; ++a)
#pragma unroll
    for (int b = 0; b < 4; ++b) acc[a][b] = 0.f;
  for (int k0 = r0; k0 < NFF; k0 += 16) {
    float4 a = *(const float4*)(Ws + (size_t)(k0 + (t >> 4)) * NFF + r0 + (t & 15) * 4);
    float4 bb = *(const float4*)(Rs + (size_t)(k0 + (t >> 4)) * NCO + c0 + (t & 15) * 4);
    __syncthreads();
    *(float4*)&As_[t >> 4][(t & 15) * 4] = a;
    *(float4*)&Bs_[t >> 4][(t & 15) * 4] = bb;
    __syncthreads();
#pragma unroll
    for (int kk = 0; kk < 16; ++kk) {
      float av[4], bv[4];
#pragma unroll
      for (int a2 = 0; a2 < 4; ++a2) av[a2] = As_[kk][ty * 4 + a2];
      *(float4*)&bv[0] = *(const float4*)&Bs_[kk][tx * 4];
#pragma unroll
      for (int a2 = 0; a2 < 4; ++a2)
#pragma unroll
        for (int b2 = 0; b2 < 4; ++b2) acc[a2][b2] = fmaf(av[a2], bv[b2], acc[a2][b2]);
    }
  }
  float s2 = 0.f;
#pragma unroll
  for (int b2 = 0; b2 < 4; ++b2) {
    int col = c0 + tx * 4 + b2;
    float4 v;
    v.x = acc[0][b2]; v.y = acc[1][b2]; v.z = acc[2][b2]; v.w = acc[3][b2];
    s2 += v.x * v.x + v.y * v.y + v.z * v.z + v.w * v.w;
    *(float4*)(Op + (size_t)col * NFF + r0 + ty * 4) = v;
  }
  __syncthreads();
  red[t] = s2;
  __syncthreads();
  for (int o = 128; o > 0; o >>= 1) {
    if (t < o) red[t] += red[t + o];
    __syncthreads();
  }
  if (t == 0) atomicAdd(&accum[s * 4 + 0], red[0]);
}

__global__ void k_final(const float* __restrict__ accum, float* __restrict__ outLogpq) {
  int s = threadIdx.x;
  if (s < NS) {
    float s2 = accum[s * 4 + 0];
    float z2 = accum[s * 4 + 1];
    float ld = accum[s * 4 + 2];
    float logP = -0.5f * LAMV * s2 + 0.5f * (float)(NCO * NFF) * logf(LAMV);
    float logQ = -0.5f * z2 + 0.5f * (float)NCO * ld;
    outLogpq[s] = logP - logQ;
  }
}

// ---------------------------------------------------------------- launch
extern "C" void kernel_launch(void* const* d_in, const int* in_sizes, int n_in,
                              void* d_out, int out_size, void* d_ws, size_t ws_size,
                              hipStream_t stream) {
  const float* X = (const float*)d_in[0];
  const float* u = (const float*)d_in[1];
  const float* lp = (const float*)d_in[2];
  const float* Z = (const float*)d_in[3];
  float* out = (float*)d_out;

  const size_t XU2 = 18874368;   // 1152*8192*2 (bf16), one s
  const size_t BM2 = 2097152;    // 128*8192*2
  const size_t FF4 = 5308416;    // 1152*1152*4
  const size_t FC4 = 589824;     // 1152*128*4
  const size_t FC = 147456;      // elems
  const size_t FF = 1327104;     // elems
  const size_t XSTR = 1048576;   // X elems per s

  // adaptive batching by workspace size (constant across calls -> graph-safe)
  int SB, kslices;
  if (ws_size >= ((size_t)206 << 20))      { SB = 8; kslices = 1; }
  else if (ws_size >= ((size_t)131 << 20)) { SB = 4; kslices = 2; }
  else                                     { SB = 2; kslices = 4; }

  char* ws = (char*)d_ws;
  size_t reg0 = (size_t)SB * XU2 + BM2;
  if (reg0 < 8 * FF4) reg0 = 8 * FF4;      // W aliases region0 after GEMMs
  unsigned short* Xu = (unsigned short*)ws;
  unsigned short* Bm = (unsigned short*)(ws + (size_t)SB * XU2);
  float* W = (float*)ws;
  size_t off = reg0;
  float* prec = (float*)(ws + off); off += 8 * FF4;
  float* XLY = (float*)(ws + off);  off += 8 * FC4;
  float* t1R = (float*)(ws + off);  off += 8 * FC4;
  float* accum = (float*)(ws + off);
  float* sp = accum + 128;

  k_sp<<<1, 64, 0, stream>>>(lp, sp);
  k_build_B<<<4096, 256, 0, stream>>>(u, sp, Bm);
  hipMemsetAsync(accum, 0, 512, stream);
  if (kslices > 1) {
    hipMemsetAsync(prec, 0, 8 * FF4, stream);
    hipMemsetAsync(XLY, 0, 8 * FC4, stream);
    k_diag_init<<<dim3(5, 8), 256, 0, stream>>>(prec);
  }

  for (int pr = 0; pr < 8 / SB; ++pr) {
    k_build_Xu<<<dim3(36864, SB), 256, 0, stream>>>(X + (size_t)pr * SB * XSTR, sp, Xu);
    k_mfma<<<dim3(54, kslices, SB), 256, 0, stream>>>(Xu, Bm,
                                                      prec + (size_t)pr * SB * FF,
                                                      XLY + (size_t)pr * SB * FC,
                                                      8192 / kslices, kslices == 1 ? 1 : 0);
  }

  // fused Cholesky: diag(0) then 17 combined steps
  k_chol_diag<<<8, 64, 0, stream>>>(prec, 0);
  for (int p = 0; p < 17; ++p) {
    int T = 17 - p;
    k_chol_step<<<dim3(T * (T + 1) / 2, 8), 256, 0, stream>>>(prec, p);
  }

  // explicit inverse W = L^{-1}
  k_invdiag<<<dim3(18, 8), 64, 0, stream>>>(prec, W, accum);
  k_invcol<<<dim3(17, 8), 256, 0, stream>>>(prec, W);

  // sample = W^T (W XLY + Z); fused reductions
  k_app1<<<dim3(18, 2, 8), 256, 0, stream>>>(W, XLY, Z, t1R, accum);
  k_app2<<<dim3(18, 2, 8), 256, 0, stream>>>(W, t1R, out, accum);
  k_final<<<1, 64, 0, stream>>>(accum, out + (size_t)NS * FC);
}

// Round 8
// 3027.823 us; speedup vs baseline: 1.1467x; 1.1467x over previous
//
#include <hip/hip_runtime.h>
#include <hip/hip_bf16.h>
#include <math.h>

#define NS    8
#define NNI   32
#define NCI   128
#define NHH   16
#define NWW   16
#define NCO   128
#define NFF   1152
#define NLL   256
#define LAMV  1152.0f

typedef short s8v __attribute__((ext_vector_type(8)));
typedef float f4v __attribute__((ext_vector_type(4)));

#define AS1 __attribute__((address_space(1)))
#define AS3 __attribute__((address_space(3)))

// ---------------------------------------------------------------- sqrt_prec table
__global__ void k_sp(const float* __restrict__ lp, float* __restrict__ sp) {
  int t = threadIdx.x;
  if (t < NNI) sp[t] = expf(0.5f * lp[t]);
}

// ---------------------------------------------------------------- build Xu (bf16), SB s per launch
__global__ __launch_bounds__(256) void k_build_Xu(const float* __restrict__ X,
                                                  const float* __restrict__ sp,
                                                  unsigned short* __restrict__ Xu) {
  unsigned z = blockIdx.y;
  unsigned idx = blockIdx.x * 256u + threadIdx.x;   // < 1152*8192
  unsigned m = idx & 8191u;
  unsigned f = idx >> 13;
  unsigned n = m >> 8, l = m & 255u, h = l >> 4, w = l & 15u;
  unsigned c = f / 9u, a = f - 9u * c;
  unsigned ki = a / 3u, kj = a - 3u * ki;
  int hi = (int)(h + ki) - 1, wi = (int)(w + kj) - 1;
  float v = 0.f;
  if (hi >= 0 && hi < NHH && wi >= 0 && wi < NWW)
    v = X[(size_t)z * 1048576 + (((size_t)n * NCI + c) << 8) + (unsigned)(hi * NWW + wi)];
  __hip_bfloat16 hv = __float2bfloat16(sp[n] * v);
  Xu[(size_t)z * (NFF * 8192) + idx] = *(unsigned short*)&hv;
}

__global__ __launch_bounds__(256) void k_build_B(const float* __restrict__ u,
                                                 const float* __restrict__ sp,
                                                 unsigned short* __restrict__ Bm) {
  unsigned idx = blockIdx.x * 256u + threadIdx.x;   // < 1,048,576
  unsigned m = idx & 8191u;
  unsigned c = idx >> 13;
  unsigned n = m >> 8, l = m & 255u;
  __hip_bfloat16 hv = __float2bfloat16(sp[n] * u[((size_t)n * NCO + c) * NLL + l]);
  Bm[idx] = *(unsigned short*)&hv;
}

__global__ void k_diag_init(float* __restrict__ prec) {
  int s = blockIdx.y;
  int i = blockIdx.x * 256 + threadIdx.x;
  if (i < NFF) prec[(size_t)s * NFF * NFF + (size_t)i * NFF + i] = LAMV;
}

// ---------------------------------------------------------------- MFMA bf16 GEMM, SB s per launch
__global__ __launch_bounds__(256) void k_mfma(const unsigned short* __restrict__ XuBase,
                                              const unsigned short* __restrict__ Bm,
                                              float* __restrict__ prec,
                                              float* __restrict__ XLY,
                                              int kLen, int direct) {
  __shared__ unsigned short As[8192];
  __shared__ unsigned short Bs[8192];
  int z = blockIdx.z;
  const unsigned short* Xu = XuBase + (size_t)z * (NFF * 8192);
  prec += (size_t)z * NFF * NFF;
  XLY += (size_t)z * NFF * NCO;
  int bx = blockIdx.x;
  int row0, col0;
  const unsigned short* Ag;
  const unsigned short* Bg;
  bool isXLX;
  if (bx < 45) {
    int b = 0;
    while ((b + 1) * (b + 2) / 2 <= bx) b++;
    row0 = b * 128;
    col0 = (bx - b * (b + 1) / 2) * 128;
    Bg = Xu + (size_t)col0 * 8192;
    isXLX = true;
  } else {
    row0 = (bx - 45) * 128;
    col0 = 0;
    Bg = Bm;
    isXLX = false;
  }
  Ag = Xu + (size_t)row0 * 8192;

  int t = threadIdx.x;
  int lane = t & 63, w = t >> 6;
  int wm = w & 1, wn = w >> 1;
  int n16 = lane & 15, q = lane >> 4;
  int srow = lane >> 3, sch = lane & 7;

  f4v acc[4][4];
#pragma unroll
  for (int i = 0; i < 4; ++i)
#pragma unroll
    for (int j = 0; j < 4; ++j) acc[i][j] = (f4v)0.f;

  int kBase = blockIdx.y * kLen;
  for (int k0 = kBase; k0 < kBase + kLen; k0 += 64) {
    __syncthreads();
#pragma unroll
    for (int it = 0; it < 4; ++it) {
      int rA = (w * 4 + it) * 8 + srow;
      int cA = (sch - rA) & 7;
      const unsigned short* gpa = Ag + (size_t)rA * 8192 + k0 + cA * 8;
      const unsigned short* gpb = Bg + (size_t)rA * 8192 + k0 + cA * 8;
      __builtin_amdgcn_global_load_lds((AS1 const void*)gpa,
                                       (AS3 void*)&As[(w * 4 + it) * 512], 16, 0, 0);
      __builtin_amdgcn_global_load_lds((AS1 const void*)gpb,
                                       (AS3 void*)&Bs[(w * 4 + it) * 512], 16, 0, 0);
    }
    __syncthreads();
#pragma unroll
    for (int kk = 0; kk < 2; ++kk) {
      s8v af[4], bf[4];
#pragma unroll
      for (int im = 0; im < 4; ++im) {
        int r = wm * 64 + im * 16 + n16;
        int slot = ((kk * 4 + q) + r) & 7;
        af[im] = *(const s8v*)&As[r * 64 + slot * 8];
      }
#pragma unroll
      for (int in = 0; in < 4; ++in) {
        int r = wn * 64 + in * 16 + n16;
        int slot = ((kk * 4 + q) + r) & 7;
        bf[in] = *(const s8v*)&Bs[r * 64 + slot * 8];
      }
#pragma unroll
      for (int im = 0; im < 4; ++im)
#pragma unroll
        for (int in = 0; in < 4; ++in)
          acc[im][in] = __builtin_amdgcn_mfma_f32_16x16x32_bf16(af[im], bf[in], acc[im][in], 0, 0, 0);
    }
  }

#pragma unroll
  for (int im = 0; im < 4; ++im)
#pragma unroll
    for (int in = 0; in < 4; ++in) {
      int gr = row0 + wm * 64 + im * 16 + q * 4;
      int gc = (isXLX ? col0 : 0) + wn * 64 + in * 16 + n16;
      if (direct) {
        if (isXLX) {
#pragma unroll
          for (int tt = 0; tt < 4; ++tt)
            prec[(size_t)(gr + tt) * NFF + gc] =
                acc[im][in][tt] + ((gr + tt) == gc ? LAMV : 0.f);
        } else {
#pragma unroll
          for (int tt = 0; tt < 4; ++tt)
            XLY[(size_t)(gr + tt) * NCO + gc] = acc[im][in][tt];
        }
      } else {
        if (isXLX) {
#pragma unroll
          for (int tt = 0; tt < 4; ++tt)
            atomicAdd(&prec[(size_t)(gr + tt) * NFF + gc], acc[im][in][tt]);
        } else {
#pragma unroll
          for (int tt = 0; tt < 4; ++tt)
            atomicAdd(&XLY[(size_t)(gr + tt) * NCO + gc], acc[im][in][tt]);
        }
      }
    }
}

// ---------------------------------------------------------------- Cholesky: diag p=0 (single wave)
__global__ __launch_bounds__(64) void k_chol_diag(float* __restrict__ P, int p) {
  int s = blockIdx.x;
  float* Ps = P + (size_t)s * NFF * NFF + (size_t)(p * 64) * NFF + p * 64;
  __shared__ float D[64][65];
  int t = threadIdx.x;
  for (int e = t; e < 1024; e += 64) {
    int r = e >> 4, cq = (e & 15) * 4;
    float4 v = *(const float4*)(Ps + (size_t)r * NFF + cq);
    D[r][cq + 0] = v.x; D[r][cq + 1] = v.y; D[r][cq + 2] = v.z; D[r][cq + 3] = v.w;
  }
  __syncthreads();
  for (int j = 0; j < 64; ++j) {
    float dj = sqrtf(D[j][j]);
    float inv = 1.0f / dj;
    float lij = 0.f;
    if (t == j) D[j][j] = dj;
    if (t > j) { lij = D[t][j] * inv; D[t][j] = lij; }
    __syncthreads();
    for (int k = j + 1; k <= t; ++k) D[t][k] = fmaf(-lij, D[k][j], D[t][k]);
    __syncthreads();
  }
  for (int e = t; e < 1024; e += 64) {
    int r = e >> 4, cq = (e & 15) * 4;
    float4 v;
    v.x = D[r][cq + 0]; v.y = D[r][cq + 1]; v.z = D[r][cq + 2]; v.w = D[r][cq + 3];
    *(float4*)(Ps + (size_t)r * NFF + cq) = v;
  }
}

// ---------------------------------------------------------------- fused chol step p
__global__ __launch_bounds__(256) void k_chol_step(float* __restrict__ P, int p) {
  int s = blockIdx.y;
  float* Ps = P + (size_t)s * NFF * NFF;
  int idx = blockIdx.x;
  int b = 0;
  while ((b + 1) * (b + 2) / 2 <= idx) b++;
  int c = idx - b * (b + 1) / 2;
  int bi = p + 1 + b, bj = p + 1 + c;
  int pc = p * 64;
  __shared__ float Ld[64][65];
  __shared__ float Ai[64][65];
  __shared__ float Aj[64][65];
  int t = threadIdx.x;
  int w = t >> 6, lane = t & 63;
  for (int e = t; e < 4096; e += 256) {
    int r = e >> 6, cc = e & 63;
    Ld[r][cc] = Ps[(size_t)(pc + r) * NFF + pc + cc];
    Ai[r][cc] = Ps[(size_t)(bi * 64 + r) * NFF + pc + cc];
  }
  if (c < b)
    for (int e = t; e < 4096; e += 256) {
      int r = e >> 6, cc = e & 63;
      Aj[r][cc] = Ps[(size_t)(bj * 64 + r) * NFF + pc + cc];
    }
  __syncthreads();
  if (w == 0) {
    for (int j = 0; j < 64; ++j) {
      float v = Ai[lane][j] / Ld[j][j];
      Ai[lane][j] = v;
      for (int k = j + 1; k < 64; ++k) Ai[lane][k] = fmaf(-v, Ld[k][j], Ai[lane][k]);
    }
  } else if (w == 1 && c < b) {
    for (int j = 0; j < 64; ++j) {
      float v = Aj[lane][j] / Ld[j][j];
      Aj[lane][j] = v;
      for (int k = j + 1; k < 64; ++k) Aj[lane][k] = fmaf(-v, Ld[k][j], Aj[lane][k]);
    }
  }
  __syncthreads();
  int tx = t & 15, ty = t >> 4;
  if (c == b) {
    for (int e = t; e < 4096; e += 256) {
      int r = e >> 6, cc = e & 63;
      Ps[(size_t)(pc + cc) * NFF + bi * 64 + r] = Ai[r][cc];
    }
    float acc[4][4];
#pragma unroll
    for (int a = 0; a < 4; ++a)
#pragma unroll
      for (int b2 = 0; b2 < 4; ++b2) acc[a][b2] = 0.f;
#pragma unroll 8
    for (int kc = 0; kc < 64; ++kc) {
      float av[4], bv[4];
#pragma unroll
      for (int a = 0; a < 4; ++a) av[a] = Ai[ty * 4 + a][kc];
#pragma unroll
      for (int b2 = 0; b2 < 4; ++b2) bv[b2] = Ai[tx * 4 + b2][kc];
#pragma unroll
      for (int a = 0; a < 4; ++a)
#pragma unroll
        for (int b2 = 0; b2 < 4; ++b2) acc[a][b2] = fmaf(av[a], bv[b2], acc[a][b2]);
    }
    if (b == 0) {
      __syncthreads();
#pragma unroll
      for (int a = 0; a < 4; ++a) {
        float4 g = *(const float4*)&Ps[(size_t)(bi * 64 + ty * 4 + a) * NFF + bi * 64 + tx * 4];
        Aj[ty * 4 + a][tx * 4 + 0] = g.x - acc[a][0];
        Aj[ty * 4 + a][tx * 4 + 1] = g.y - acc[a][1];
        Aj[ty * 4 + a][tx * 4 + 2] = g.z - acc[a][2];
        Aj[ty * 4 + a][tx * 4 + 3] = g.w - acc[a][3];
      }
      __syncthreads();
      for (int j = 0; j < 64; ++j) {
        if (w == 0) {
          float dj = sqrtf(Aj[j][j]);
          float inv = 1.0f / dj;
          float lij = 0.f;
          if (lane == j) Aj[j][j] = dj;
          if (lane > j) { lij = Aj[lane][j] * inv; Aj[lane][j] = lij; }
          for (int k = j + 1; k <= lane; ++k) Aj[lane][k] = fmaf(-lij, Aj[k][j], Aj[lane][k]);
        }
        __syncthreads();
      }
      for (int e = t; e < 4096; e += 256) {
        int r = e >> 6, cc = e & 63;
        Ps[(size_t)(bi * 64 + r) * NFF + bi * 64 + cc] = Aj[r][cc];
      }
    } else {
#pragma unroll
      for (int a = 0; a < 4; ++a) {
        float4* cp = (float4*)&Ps[(size_t)(bi * 64 + ty * 4 + a) * NFF + bi * 64 + tx * 4];
        float4 cv = *cp;
        cv.x -= acc[a][0]; cv.y -= acc[a][1]; cv.z -= acc[a][2]; cv.w -= acc[a][3];
        *cp = cv;
      }
    }
  } else {
    float acc[4][4];
#pragma unroll
    for (int a = 0; a < 4; ++a)
#pragma unroll
      for (int b2 = 0; b2 < 4; ++b2) acc[a][b2] = 0.f;
#pragma unroll 8
    for (int kc = 0; kc < 64; ++kc) {
      float av[4], bv[4];
#pragma unroll
      for (int a = 0; a < 4; ++a) av[a] = Ai[ty * 4 + a][kc];
#pragma unroll
      for (int b2 = 0; b2 < 4; ++b2) bv[b2] = Aj[tx * 4 + b2][kc];
#pragma unroll
      for (int a = 0; a < 4; ++a)
#pragma unroll
        for (int b2 = 0; b2 < 4; ++b2) acc[a][b2] = fmaf(av[a], bv[b2], acc[a][b2]);
    }
#pragma unroll
    for (int a = 0; a < 4; ++a) {
      float4* cp = (float4*)&Ps[(size_t)(bi * 64 + ty * 4 + a) * NFF + bj * 64 + tx * 4];
      float4 cv = *cp;
      cv.x -= acc[a][0]; cv.y -= acc[a][1]; cv.z -= acc[a][2]; cv.w -= acc[a][3];
      *cp = cv;
    }
  }
}

// ---------------------------------------------------------------- inverse diag blocks + logdet
__global__ __launch_bounds__(64) void k_invdiag(const float* __restrict__ P,
                                                float* __restrict__ W,
                                                float* __restrict__ accum) {
  int ib = blockIdx.x, s = blockIdx.y;
  const float* Ps = P + (size_t)s * NFF * NFF + (size_t)(ib * 64) * NFF + ib * 64;
  float* Ws = W + (size_t)s * NFF * NFF + (size_t)(ib * 64) * NFF + ib * 64;
  __shared__ float Lt[64][65];
  __shared__ float xc[64][66];
  int t = threadIdx.x;
  for (int e = t; e < 4096; e += 64)
    Lt[e >> 6][e & 63] = Ps[(size_t)(e >> 6) * NFF + (e & 63)];
  __syncthreads();
  float lg = logf(Lt[t][t]);
#pragma unroll
  for (int o = 32; o; o >>= 1) lg += __shfl_down(lg, o, 64);
  if (t == 0) atomicAdd(&accum[s * 4 + 2], 2.f * lg);
  for (int j = 0; j < 64; ++j) {
    float v = (j == t) ? 1.f : 0.f;
    for (int k = t; k < j; ++k) v = fmaf(-Lt[j][k], xc[k][t], v);
    xc[j][t] = v / Lt[j][j];
  }
  for (int j = 0; j < 64; ++j)
    Ws[(size_t)j * NFF + t] = (j >= t) ? xc[j][t] : 0.f;
}

// ---------------------------------------------------------------- level-1 pair inverse (fused):
// W[2p+1][2p] = -D2 * L21 * D1, all 64x64, one block per (pair,s)
__global__ __launch_bounds__(256) void k_inv1(const float* __restrict__ P,
                                              float* __restrict__ W) {
  int p = blockIdx.x, s = blockIdx.y;
  int J = 2 * p, I = 2 * p + 1;
  const float* Ps = P + (size_t)s * NFF * NFF;
  float* Ws = W + (size_t)s * NFF * NFF;
  __shared__ float Ak[64][65];   // L21 as [k][i] (from transposed-upper copy)
  __shared__ float Bk[64][65];   // D1 [k][j]
  __shared__ float Dk[64][65];   // D2 as [k][i]
  __shared__ float Tt[64][65];   // T = L21*D1, [k(=i)][j]
  int t = threadIdx.x, tx = t & 15, ty = t >> 4;
  for (int e = t; e < 4096; e += 256) {
    int r = e >> 6, cc = e & 63;
    Ak[r][cc] = Ps[(size_t)(J * 64 + r) * NFF + I * 64 + cc];   // upper copy row
    Bk[r][cc] = Ws[(size_t)(J * 64 + r) * NFF + J * 64 + cc];
  }
  {
    int i = t >> 2;
#pragma unroll
    for (int it = 0; it < 4; ++it) {
      int kq = (t & 3) * 4 + it * 16;
      float4 a = *(const float4*)&Ws[(size_t)(I * 64 + i) * NFF + I * 64 + kq];
      Dk[kq + 0][i] = a.x; Dk[kq + 1][i] = a.y; Dk[kq + 2][i] = a.z; Dk[kq + 3][i] = a.w;
    }
  }
  __syncthreads();
  float acc[4][4];
#pragma unroll
  for (int a = 0; a < 4; ++a)
#pragma unroll
    for (int b = 0; b < 4; ++b) acc[a][b] = 0.f;
#pragma unroll 8
  for (int kk = 0; kk < 64; ++kk) {
    float av[4], bv[4];
#pragma unroll
    for (int a = 0; a < 4; ++a) av[a] = Ak[kk][ty * 4 + a];
#pragma unroll
    for (int b = 0; b < 4; ++b) bv[b] = Bk[kk][tx * 4 + b];
#pragma unroll
    for (int a = 0; a < 4; ++a)
#pragma unroll
      for (int b = 0; b < 4; ++b) acc[a][b] = fmaf(av[a], bv[b], acc[a][b]);
  }
#pragma unroll
  for (int a = 0; a < 4; ++a)
#pragma unroll
    for (int b = 0; b < 4; ++b) Tt[ty * 4 + a][tx * 4 + b] = acc[a][b];
  __syncthreads();
  float a2[4][4];
#pragma unroll
  for (int a = 0; a < 4; ++a)
#pragma unroll
    for (int b = 0; b < 4; ++b) a2[a][b] = 0.f;
#pragma unroll 8
  for (int kk = 0; kk < 64; ++kk) {
    float av[4], bv[4];
#pragma unroll
    for (int a = 0; a < 4; ++a) av[a] = Dk[kk][ty * 4 + a];
#pragma unroll
    for (int b = 0; b < 4; ++b) bv[b] = Tt[kk][tx * 4 + b];
#pragma unroll
    for (int a = 0; a < 4; ++a)
#pragma unroll
      for (int b = 0; b < 4; ++b) a2[a][b] = fmaf(av[a], bv[b], a2[a][b]);
  }
#pragma unroll
  for (int a = 0; a < 4; ++a) {
    float4 o;
    o.x = -a2[a][0]; o.y = -a2[a][1]; o.z = -a2[a][2]; o.w = -a2[a][3];
    *(float4*)&Ws[(size_t)(I * 64 + ty * 4 + a) * NFF + J * 64 + tx * 4] = o;
  }
}

// ---------------------------------------------------------------- level kernel A: T = L21 * W11
// grid (n2, nc, pairs*8); o = (z>>3)*2*n1; tile col c = c0off + blockIdx.y
__global__ __launch_bounds__(256) void k_invA(const float* __restrict__ P,
                                              const float* __restrict__ W,
                                              float* __restrict__ Tb,
                                              int n1, int c0off) {
  int r = blockIdx.x, ccb = blockIdx.y;
  int pq = blockIdx.z >> 3, s = blockIdx.z & 7;
  int o = pq * 2 * n1;
  int n2 = gridDim.x, ldT = gridDim.y * 64;
  int I = o + n1 + r, c = c0off + ccb;
  const float* Ps = P + (size_t)s * NFF * NFF;
  const float* Ws = W + (size_t)s * NFF * NFF;
  float* Ts = Tb + (size_t)s * 147456 + (size_t)pq * (n2 * 64) * ldT;
  __shared__ float Aks[16][68];
  __shared__ float Bks[16][68];
  int t = threadIdx.x, tx = t & 15, ty = t >> 4;
  float acc[4][4];
#pragma unroll
  for (int a = 0; a < 4; ++a)
#pragma unroll
    for (int b = 0; b < 4; ++b) acc[a][b] = 0.f;
  for (int kb = c; kb < n1; ++kb) {
    const float* up = Ps + (size_t)((o + kb) * 64) * NFF + I * 64;     // upper: L[I][kb] as [k][i]
    const float* wp = Ws + (size_t)((o + kb) * 64) * NFF + (o + c) * 64;
    for (int k0 = 0; k0 < 64; k0 += 16) {
      float4 a = *(const float4*)(up + (size_t)(k0 + ty) * NFF + tx * 4);
      float4 b = *(const float4*)(wp + (size_t)(k0 + ty) * NFF + tx * 4);
      __syncthreads();
      *(float4*)&Aks[ty][tx * 4] = a;
      *(float4*)&Bks[ty][tx * 4] = b;
      __syncthreads();
#pragma unroll
      for (int kk = 0; kk < 16; ++kk) {
        float av[4], bv[4];
#pragma unroll
        for (int a2 = 0; a2 < 4; ++a2) av[a2] = Aks[kk][ty * 4 + a2];
        *(float4*)&bv[0] = *(const float4*)&Bks[kk][tx * 4];
#pragma unroll
        for (int a2 = 0; a2 < 4; ++a2)
#pragma unroll
          for (int b2 = 0; b2 < 4; ++b2) acc[a2][b2] = fmaf(av[a2], bv[b2], acc[a2][b2]);
      }
    }
  }
#pragma unroll
  for (int a = 0; a < 4; ++a) {
    float4 v;
    v.x = acc[a][0]; v.y = acc[a][1]; v.z = acc[a][2]; v.w = acc[a][3];
    *(float4*)(Ts + (size_t)(r * 64 + ty * 4 + a) * ldT + ccb * 64 + tx * 4) = v;
  }
}

// ---------------------------------------------------------------- level kernel B: W21 = -W22 * T
__global__ __launch_bounds__(256) void k_invB(float* __restrict__ W,
                                              const float* __restrict__ Tb,
                                              int n1, int c0off) {
  int r = blockIdx.x, ccb = blockIdx.y;
  int pq = blockIdx.z >> 3, s = blockIdx.z & 7;
  int o = pq * 2 * n1;
  int n2 = gridDim.x, ldT = gridDim.y * 64;
  int I = o + n1 + r, c = c0off + ccb;
  float* Ws = W + (size_t)s * NFF * NFF;
  const float* Ts = Tb + (size_t)s * 147456 + (size_t)pq * (n2 * 64) * ldT;
  __shared__ float Aks[16][68];
  __shared__ float Bks[16][68];
  int t = threadIdx.x, tx = t & 15, ty = t >> 4;
  float acc[4][4];
#pragma unroll
  for (int a = 0; a < 4; ++a)
#pragma unroll
    for (int b = 0; b < 4; ++b) acc[a][b] = 0.f;
  for (int kb = 0; kb <= r; ++kb) {
    const float* ap = Ws + (size_t)(I * 64) * NFF + (o + n1 + kb) * 64;   // W22[r][kb] row-major
    const float* tp = Ts + (size_t)(kb * 64) * ldT + ccb * 64;
    for (int k0 = 0; k0 < 64; k0 += 16) {
      float4 a = *(const float4*)(ap + (size_t)(t >> 2) * NFF + k0 + (t & 3) * 4);
      float4 b = *(const float4*)(tp + (size_t)(k0 + ty) * ldT + tx * 4);
      __syncthreads();
      Aks[(t & 3) * 4 + 0][t >> 2] = a.x;
      Aks[(t & 3) * 4 + 1][t >> 2] = a.y;
      Aks[(t & 3) * 4 + 2][t >> 2] = a.z;
      Aks[(t & 3) * 4 + 3][t >> 2] = a.w;
      *(float4*)&Bks[ty][tx * 4] = b;
      __syncthreads();
#pragma unroll
      for (int kk = 0; kk < 16; ++kk) {
        float av[4], bv[4];
#pragma unroll
        for (int a2 = 0; a2 < 4; ++a2) av[a2] = Aks[kk][ty * 4 + a2];
        *(float4*)&bv[0] = *(const float4*)&Bks[kk][tx * 4];
#pragma unroll
        for (int a2 = 0; a2 < 4; ++a2)
#pragma unroll
          for (int b2 = 0; b2 < 4; ++b2) acc[a2][b2] = fmaf(av[a2], bv[b2], acc[a2][b2]);
      }
    }
  }
#pragma unroll
  for (int a = 0; a < 4; ++a) {
    float4 v;
    v.x = -acc[a][0]; v.y = -acc[a][1]; v.z = -acc[a][2]; v.w = -acc[a][3];
    *(float4*)&Ws[(size_t)(I * 64 + ty * 4 + a) * NFF + (o + c) * 64 + tx * 4] = v;
  }
}

// ---------------------------------------------------------------- apply: t1R = W*XLY + Z (+sumZ^2)
__global__ __launch_bounds__(256) void k_app1(const float* __restrict__ W,
                                              const float* __restrict__ XLY,
                                              const float* __restrict__ Z,
                                              float* __restrict__ t1R,
                                              float* __restrict__ accum) {
  int rb = blockIdx.x, ch = blockIdx.y, s = blockIdx.z;
  int r0 = rb * 64, c0 = ch * 64;
  const float* Ws = W + (size_t)s * NFF * NFF;
  const float* Ys = XLY + (size_t)s * NFF * NCO;
  const float* Zs = Z + (size_t)s * NFF * NCO;
  float* Os = t1R + (size_t)s * NFF * NCO;
  __shared__ float As_[16][68];
  __shared__ float Bs_[16][68];
  __shared__ float red[256];
  int t = threadIdx.x, tx = t & 15, ty = t >> 4;
  float acc[4][4];
#pragma unroll
  for (int a = 0; a < 4; ++a)
#pragma unroll
    for (int b = 0; b < 4; ++b) acc[a][b] = 0.f;
  int kmax = r0 + 64;
  for (int k0 = 0; k0 < kmax; k0 += 16) {
    float4 a = *(const float4*)(Ws + (size_t)(r0 + (t >> 2)) * NFF + k0 + (t & 3) * 4);
    float4 bb = *(const float4*)(Ys + (size_t)(k0 + (t >> 4)) * NCO + c0 + (t & 15) * 4);
    __syncthreads();
    As_[(t & 3) * 4 + 0][t >> 2] = a.x; As_[(t & 3) * 4 + 1][t >> 2] = a.y;
    As_[(t & 3) * 4 + 2][t >> 2] = a.z; As_[(t & 3) * 4 + 3][t >> 2] = a.w;
    *(float4*)&Bs_[t >> 4][(t & 15) * 4] = bb;
    __syncthreads();
#pragma unroll
    for (int kk = 0; kk < 16; ++kk) {
      float av[4], bv[4];
#pragma unroll
      for (int a2 = 0; a2 < 4; ++a2) av[a2] = As_[kk][ty * 4 + a2];
      *(float4*)&bv[0] = *(const float4*)&Bs_[kk][tx * 4];
#pragma unroll
      for (int a2 = 0; a2 < 4; ++a2)
#pragma unroll
        for (int b2 = 0; b2 < 4; ++b2) acc[a2][b2] = fmaf(av[a2], bv[b2], acc[a2][b2]);
    }
  }
  float z2 = 0.f;
#pragma unroll
  for (int a2 = 0; a2 < 4; ++a2) {
    int row = r0 + ty * 4 + a2;
    const float* zp = Zs + (size_t)row * NCO + c0 + tx * 4;
    float* op = Os + (size_t)row * NCO + c0 + tx * 4;
    float4 z0 = *(const float4*)zp;
    float4 v0;
    v0.x = acc[a2][0] + z0.x; v0.y = acc[a2][1] + z0.y;
    v0.z = acc[a2][2] + z0.z; v0.w = acc[a2][3] + z0.w;
    z2 += z0.x * z0.x + z0.y * z0.y + z0.z * z0.z + z0.w * z0.w;
    *(float4*)op = v0;
  }
  __syncthreads();
  red[t] = z2;
  __syncthreads();
  for (int o = 128; o > 0; o >>= 1) {
    if (t < o) red[t] += red[t + o];
    __syncthreads();
  }
  if (t == 0) atomicAdd(&accum[s * 4 + 1], red[0]);
}

// ---------------------------------------------------------------- apply: sample = W^T * t1R (+sum S^2)
__global__ __launch_bounds__(256) void k_app2(const float* __restrict__ W,
                                              const float* __restrict__ t1R,
                                              float* __restrict__ sout,
                                              float* __restrict__ accum) {
  int rb = blockIdx.x, ch = blockIdx.y, s = blockIdx.z;
  int r0 = rb * 64, c0 = ch * 64;
  const float* Ws = W + (size_t)s * NFF * NFF;
  const float* Rs = t1R + (size_t)s * NFF * NCO;
  float* Op = sout + (size_t)s * NCO * NFF;
  __shared__ float As_[16][68];
  __shared__ float Bs_[16][68];
  __shared__ float red[256];
  int t = threadIdx.x, tx = t & 15, ty = t >> 4;
  float acc[4][4];
#pragma unroll
  for (int a = 0; a < 4; ++a)
#pragma unroll
    for (int b = 0; b < 4; ++b) acc[a][b] = 0.f;
  for (int k0 = r0; k0 < NFF; k0 += 16) {
    float4 a = *(const float4*)(Ws + (size_t)(k0 + (t >> 4)) * NFF + r0 + (t & 15) * 4);
    float4 bb = *(const float4*)(Rs + (size_t)(k0 + (t >> 4)) * NCO + c0 + (t & 15) * 4);
    __syncthreads();
    *(float4*)&As_[t >> 4][(t & 15) * 4] = a;
    *(float4*)&Bs_[t >> 4][(t & 15) * 4] = bb;
    __syncthreads();
#pragma unroll
    for (int kk = 0; kk < 16; ++kk) {
      float av[4], bv[4];
#pragma unroll
      for (int a2 = 0; a2 < 4; ++a2) av[a2] = As_[kk][ty * 4 + a2];
      *(float4*)&bv[0] = *(const float4*)&Bs_[kk][tx * 4];
#pragma unroll
      for (int a2 = 0; a2 < 4; ++a2)
#pragma unroll
        for (int b2 = 0; b2 < 4; ++b2) acc[a2][b2] = fmaf(av[a2], bv[b2], acc[a2][b2]);
    }
  }
  float s2 = 0.f;
#pragma unroll
  for (int b2 = 0; b2 < 4; ++b2) {
    int col = c0 + tx * 4 + b2;
    float4 v;
    v.x = acc[0][b2]; v.y = acc[1][b2]; v.z = acc[2][b2]; v.w = acc[3][b2];
    s2 += v.x * v.x + v.y * v.y + v.z * v.z + v.w * v.w;
    *(float4*)(Op + (size_t)col * NFF + r0 + ty * 4) = v;
  }
  __syncthreads();
  red[t] = s2;
  __syncthreads();
  for (int o = 128; o > 0; o >>= 1) {
    if (t < o) red[t] += red[t + o];
    __syncthreads();
  }
  if (t == 0) atomicAdd(&accum[s * 4 + 0], red[0]);
}

__global__ void k_final(const float* __restrict__ accum, float* __restrict__ outLogpq) {
  int s = threadIdx.x;
  if (s < NS) {
    float s2 = accum[s * 4 + 0];
    float z2 = accum[s * 4 + 1];
    float ld = accum[s * 4 + 2];
    float logP = -0.5f * LAMV * s2 + 0.5f * (float)(NCO * NFF) * logf(LAMV);
    float logQ = -0.5f * z2 + 0.5f * (float)NCO * ld;
    outLogpq[s] = logP - logQ;
  }
}

// ---------------------------------------------------------------- launch
extern "C" void kernel_launch(void* const* d_in, const int* in_sizes, int n_in,
                              void* d_out, int out_size, void* d_ws, size_t ws_size,
                              hipStream_t stream) {
  const float* X = (const float*)d_in[0];
  const float* u = (const float*)d_in[1];
  const float* lp = (const float*)d_in[2];
  const float* Z = (const float*)d_in[3];
  float* out = (float*)d_out;

  const size_t XU2 = 18874368;   // 1152*8192*2 (bf16), one s
  const size_t BM2 = 2097152;    // 128*8192*2
  const size_t FF4 = 5308416;    // 1152*1152*4
  const size_t FC4 = 589824;     // 1152*128*4
  const size_t FC = 147456;      // elems
  const size_t FF = 1327104;     // elems
  const size_t XSTR = 1048576;   // X elems per s

  int SB, kslices;
  if (ws_size >= ((size_t)206 << 20))      { SB = 8; kslices = 1; }
  else if (ws_size >= ((size_t)131 << 20)) { SB = 4; kslices = 2; }
  else                                     { SB = 2; kslices = 4; }

  char* ws = (char*)d_ws;
  size_t reg0 = (size_t)SB * XU2 + BM2;
  if (reg0 < 8 * FF4) reg0 = 8 * FF4;      // W aliases region0 after GEMMs
  unsigned short* Xu = (unsigned short*)ws;
  unsigned short* Bm = (unsigned short*)(ws + (size_t)SB * XU2);
  float* W = (float*)ws;
  size_t off = reg0;
  float* prec = (float*)(ws + off); off += 8 * FF4;
  float* XLY = (float*)(ws + off);  off += 8 * FC4;
  float* t1R = (float*)(ws + off);  off += 8 * FC4;   // also level-T scratch
  float* accum = (float*)(ws + off);
  float* sp = accum + 128;

  k_sp<<<1, 64, 0, stream>>>(lp, sp);
  k_build_B<<<4096, 256, 0, stream>>>(u, sp, Bm);
  hipMemsetAsync(accum, 0, 512, stream);
  if (kslices > 1) {
    hipMemsetAsync(prec, 0, 8 * FF4, stream);
    hipMemsetAsync(XLY, 0, 8 * FC4, stream);
    k_diag_init<<<dim3(5, 8), 256, 0, stream>>>(prec);
  }

  for (int pr = 0; pr < 8 / SB; ++pr) {
    k_build_Xu<<<dim3(36864, SB), 256, 0, stream>>>(X + (size_t)pr * SB * XSTR, sp, Xu);
    k_mfma<<<dim3(54, kslices, SB), 256, 0, stream>>>(Xu, Bm,
                                                      prec + (size_t)pr * SB * FF,
                                                      XLY + (size_t)pr * SB * FC,
                                                      8192 / kslices, kslices == 1 ? 1 : 0);
  }

  // fused Cholesky: diag(0) then 17 combined steps
  k_chol_diag<<<8, 64, 0, stream>>>(prec, 0);
  for (int p = 0; p < 17; ++p) {
    int T = 17 - p;
    k_chol_step<<<dim3(T * (T + 1) / 2, 8), 256, 0, stream>>>(prec, p);
  }

  // W = L^{-1} via recursive block doubling
  k_invdiag<<<dim3(18, 8), 64, 0, stream>>>(prec, W, accum);
  k_inv1<<<dim3(9, 8), 256, 0, stream>>>(prec, W);                       // pairs of 64
  k_invA<<<dim3(2, 2, 32), 256, 0, stream>>>(prec, W, t1R, 2, 0);        // n=128 pairs
  k_invB<<<dim3(2, 2, 32), 256, 0, stream>>>(W, t1R, 2, 0);
  k_invA<<<dim3(4, 4, 16), 256, 0, stream>>>(prec, W, t1R, 4, 0);        // n=256 pairs
  k_invB<<<dim3(4, 4, 16), 256, 0, stream>>>(W, t1R, 4, 0);
  k_invA<<<dim3(8, 4, 8), 256, 0, stream>>>(prec, W, t1R, 8, 0);         // n=512, cols 0-3
  k_invB<<<dim3(8, 4, 8), 256, 0, stream>>>(W, t1R, 8, 0);
  k_invA<<<dim3(8, 4, 8), 256, 0, stream>>>(prec, W, t1R, 8, 4);         // n=512, cols 4-7
  k_invB<<<dim3(8, 4, 8), 256, 0, stream>>>(W, t1R, 8, 4);
  k_invA<<<dim3(2, 16, 8), 256, 0, stream>>>(prec, W, t1R, 16, 0);       // (1024,128) final
  k_invB<<<dim3(2, 16, 8), 256, 0, stream>>>(W, t1R, 16, 0);

  // sample = W^T (W XLY + Z); fused reductions
  k_app1<<<dim3(18, 2, 8), 256, 0, stream>>>(W, XLY, Z, t1R, accum);
  k_app2<<<dim3(18, 2, 8), 256, 0, stream>>>(W, t1R, out, accum);
  k_final<<<1, 64, 0, stream>>>(accum, out + (size_t)NS * FC);
}